// Round 14
// baseline (812.488 us; speedup 1.0000x reference)
//
#include <hip/hip_runtime.h>
#include <math.h>

#define NNODES 100000
#define NEDGES 1600000
#define FD 128
#define NCLS 40
#define NB_SCAN ((NNODES + 1023) / 1024)   // 98
#define PGRID ((NNODES + 63) / 64)         // 1563 proj blocks
#define FGRID ((NEDGES + 255) / 256)       // 6250 fill/hist blocks

typedef __attribute__((ext_vector_type(8))) short short8v;   // 8 x bf16 (4 VGPR)
typedef __attribute__((ext_vector_type(4))) float f32x4;

__device__ __forceinline__ unsigned short f32_to_bf16_rne(float f) {
    unsigned int u = __float_as_uint(f);
    unsigned int r = u + 0x7fff + ((u >> 16) & 1);
    return (unsigned short)(r >> 16);
}
__device__ __forceinline__ float bf16_to_f32(unsigned short h) {
    return __uint_as_float(((unsigned int)h) << 16);
}

// ---- per-block edge-dtype self-detection (int64 vs harness-narrowed int32) ----

__device__ __forceinline__ int detect_is32_block(const void* eiv, int* s_flag) {
    if (threadIdx.x < 64) {
        const long long* p = (const long long*)eiv;
        long long v = p[(size_t)threadIdx.x * (NEDGES / 64)];
        unsigned long long bad = __ballot(v < 0 || v >= (long long)NNODES);
        if (threadIdx.x == 0) *s_flag = (bad != 0ULL);
    }
    __syncthreads();
    return *s_flag;
}

__device__ __forceinline__ void load_edge(const void* eiv, int is32, int e, int& s, int& d) {
    if (is32) {
        const int* p = (const int*)eiv;
        s = p[e]; d = p[NEDGES + e];
    } else {
        const long long* p = (const long long*)eiv;
        s = (int)p[e]; d = (int)p[NEDGES + e];
    }
}

// ---------------- CSR build (dst-sorted adjacency), built once per call ----------------

__global__ __launch_bounds__(256) void hist_kernel(const void* __restrict__ eiv,
                                                   int* __restrict__ row_ptr) {
    __shared__ int sflag;
    int is32 = detect_is32_block(eiv, &sflag);
    int e = blockIdx.x * blockDim.x + threadIdx.x;
    if (e < NEDGES) {
        int s, d;
        load_edge(eiv, is32, e, s, d);
        atomicAdd(&row_ptr[d + 1], 1);
    }
}

// 98 blocks: local inclusive scan of 1024 counts
__global__ __launch_bounds__(1024) void scan_blk(int* __restrict__ row_ptr,
                                                 int* __restrict__ cursor,
                                                 int* __restrict__ blk_tot) {
    __shared__ int wtot[16];
    __shared__ int woff[16];
    int t = threadIdx.x, lane = t & 63, wid = t >> 6;
    int i = blockIdx.x * 1024 + t;
    int c = (i < NNODES) ? row_ptr[1 + i] : 0;
    int x = c;
    #pragma unroll
    for (int off = 1; off < 64; off <<= 1) {
        int y = __shfl_up(x, off, 64);
        if (lane >= off) x += y;
    }
    if (lane == 63) wtot[wid] = x;
    __syncthreads();
    if (t < 16) {
        int v = wtot[t];
        #pragma unroll
        for (int off = 1; off < 16; off <<= 1) {
            int y = __shfl_up(v, off, 64);
            if (t >= off) v += y;
        }
        woff[t] = v;
    }
    __syncthreads();
    int excl = (wid == 0) ? 0 : woff[wid - 1];
    int incl = x + excl;
    if (i < NNODES) {
        row_ptr[1 + i] = incl;
        cursor[i]      = incl - c;
    }
    if (t == 0) blk_tot[blockIdx.x] = woff[15];
}

// 1 block x 128: exclusive scan of the 98 block totals.
__global__ void scan_tops(const int* __restrict__ blk_tot, int* __restrict__ blk_off) {
    __shared__ int s[128];
    int t = threadIdx.x;
    int c0 = (t < NB_SCAN) ? blk_tot[t] : 0;
    s[t] = c0;
    __syncthreads();
    for (int d = 1; d < 128; d <<= 1) {
        int v = (t >= d) ? s[t - d] : 0;
        __syncthreads();
        s[t] += v;
        __syncthreads();
    }
    if (t < NB_SCAN) blk_off[t] = s[t] - c0;
}

// 98 blocks: add block offsets.
__global__ __launch_bounds__(1024) void scan_add(int* __restrict__ row_ptr,
                                                 int* __restrict__ cursor,
                                                 const int* __restrict__ blk_off) {
    int i = blockIdx.x * 1024 + threadIdx.x;
    if (i < NNODES) {
        int o = blk_off[blockIdx.x];
        row_ptr[1 + i] += o;
        cursor[i]      += o;
    }
}

// ---------------- W pack: all 8 slots in one launch ----------------

__global__ void pack_all(
    const float* __restrict__ W0, const float* __restrict__ W1,
    const float* __restrict__ W2, const float* __restrict__ W3,
    const float* __restrict__ W4, const float* __restrict__ W5,
    const float* __restrict__ W6, const float* __restrict__ W7,
    short* __restrict__ Whi, short* __restrict__ Wlo)
{
    int slot = blockIdx.x >> 5;        // 0..7
    int ctkk = blockIdx.x & 31;        // ct*4+kk
    const float* W = (slot == 0) ? W0 : (slot == 1) ? W1 : (slot == 2) ? W2 :
                     (slot == 3) ? W3 : (slot == 4) ? W4 : (slot == 5) ? W5 :
                     (slot == 6) ? W6 : W7;
    int lane = threadIdx.x;            // 64
    int ct = ctkk >> 2, kk = ctkk & 3;
    int col = ct * 16 + (lane & 15);
    int k0 = kk * 32 + (lane >> 4) * 8;
    short8v h, l;
    #pragma unroll
    for (int j = 0; j < 8; j++) {
        float v = W[(size_t)(k0 + j) * FD + col];
        unsigned short hh = f32_to_bf16_rne(v);
        float rem = v - bf16_to_f32(hh);
        h[j] = (short)hh;
        l[j] = (short)f32_to_bf16_rne(rem);
    }
    size_t o = ((size_t)slot * 32 + ctkk) * 512 + (size_t)lane * 8;
    *(short8v*)(Whi + o) = h;
    *(short8v*)(Wlo + o) = l;
}

// ---------------- proj body: fused 4-projection GEMM via bf16 MFMA, fp32-split 3-pass ----

__device__ __forceinline__ void proj_body(
    int bx,
    const float* __restrict__ X,
    const short* __restrict__ Whi, const short* __restrict__ Wlo,
    const float* __restrict__ b0, const float* __restrict__ b1,
    const float* __restrict__ b2, const float* __restrict__ b3,
    float* __restrict__ Q, unsigned short* __restrict__ KV, float* __restrict__ SKIP)
{
    int wid = threadIdx.x >> 6, lane = threadIdx.x & 63;
    int rowbase = bx * 64 + wid * 16;
    int r = lane & 15, q = lane >> 4;
    int row = rowbase + r;

    short8v xh[4], xl[4];
    if (row < NNODES) {
        const float* xp = X + (size_t)row * FD + q * 8;
        #pragma unroll
        for (int kk = 0; kk < 4; kk++) {
            float4 v0 = *(const float4*)(xp + kk * 32);
            float4 v1 = *(const float4*)(xp + kk * 32 + 4);
            float vv[8] = {v0.x, v0.y, v0.z, v0.w, v1.x, v1.y, v1.z, v1.w};
            #pragma unroll
            for (int j = 0; j < 8; j++) {
                unsigned short h = f32_to_bf16_rne(vv[j]);
                float rem = vv[j] - bf16_to_f32(h);
                xh[kk][j] = (short)h;
                xl[kk][j] = (short)f32_to_bf16_rne(rem);
            }
        }
    } else {
        short8v z = {0, 0, 0, 0, 0, 0, 0, 0};
        #pragma unroll
        for (int kk = 0; kk < 4; kk++) { xh[kk] = z; xl[kk] = z; }
    }

    #pragma unroll
    for (int pt = 0; pt < 4; pt++) {
        const float* bias = (pt == 0) ? b0 : (pt == 1) ? b1 : (pt == 2) ? b2 : b3;
        #pragma unroll
        for (int ct = 0; ct < 8; ct++) {
            const short* wp = Whi + ((size_t)(pt * 8 + ct) * 4) * 512 + (size_t)lane * 8;
            const short* lp = Wlo + ((size_t)(pt * 8 + ct) * 4) * 512 + (size_t)lane * 8;
            f32x4 acc = {0.f, 0.f, 0.f, 0.f};
            #pragma unroll
            for (int kk = 0; kk < 4; kk++) {
                short8v bh = *(const short8v*)(wp + kk * 512);
                short8v bl = *(const short8v*)(lp + kk * 512);
                acc = __builtin_amdgcn_mfma_f32_16x16x32_bf16(xh[kk], bh, acc, 0, 0, 0);
                acc = __builtin_amdgcn_mfma_f32_16x16x32_bf16(xl[kk], bh, acc, 0, 0, 0);
                acc = __builtin_amdgcn_mfma_f32_16x16x32_bf16(xh[kk], bl, acc, 0, 0, 0);
            }
            float bb = bias[ct * 16 + r];
            int e = ct * 16 + r;
            #pragma unroll
            for (int j = 0; j < 4; j++) {
                int ro = rowbase + q * 4 + j;          // D: col=lane&15, row=(lane>>4)*4+j
                if (ro < NNODES) {
                    float val = acc[j] + bb;
                    if (pt == 0)      Q[(size_t)ro * FD + e] = val;
                    else if (pt == 1) KV[(size_t)ro * 256 + 2 * e]     = f32_to_bf16_rne(val);
                    else if (pt == 2) KV[(size_t)ro * 256 + 2 * e + 1] = f32_to_bf16_rne(val);
                    else              SKIP[(size_t)ro * FD + e] = val;
                }
            }
        }
    }
}

// standalone proj (layer 2)
__global__ __launch_bounds__(256) void proj_gemm_mfma(
    const float* __restrict__ X,
    const short* __restrict__ Whi, const short* __restrict__ Wlo,
    const float* __restrict__ b0, const float* __restrict__ b1,
    const float* __restrict__ b2, const float* __restrict__ b3,
    float* __restrict__ Q, unsigned short* __restrict__ KV, float* __restrict__ SKIP)
{
    proj_body(blockIdx.x, X, Whi, Wlo, b0, b1, b2, b3, Q, KV, SKIP);
}

// ---- fused + INTERLEAVED: b%5==0 -> proj block b/5; else fill block (b - b/5 - 1) ----
// 1:4 stripe keeps proj and fill blocks co-resident on every CU from t=0, so fill's
// atomic-latency waits hide under proj's MFMA/VALU work (R12 showed index-ordered
// blocks time-share instead: machine fills with proj first, fill runs after).

__global__ __launch_bounds__(256) void proj1_fill(
    const float* __restrict__ X,
    const short* __restrict__ Whi, const short* __restrict__ Wlo,
    const float* __restrict__ b0, const float* __restrict__ b1,
    const float* __restrict__ b2, const float* __restrict__ b3,
    float* __restrict__ Q, unsigned short* __restrict__ KV, float* __restrict__ SKIP,
    const void* __restrict__ eiv, int* __restrict__ cursor, int* __restrict__ src_sorted)
{
    int b = blockIdx.x;
    if (b % 5 == 0) {
        proj_body(b / 5, X, Whi, Wlo, b0, b1, b2, b3, Q, KV, SKIP);
    } else {
        __shared__ int sflag;
        int is32 = detect_is32_block(eiv, &sflag);
        int fb = b - b / 5 - 1;                 // bijective onto [0, 4*PGRID)
        int e = fb * 256 + threadIdx.x;
        if (e < NEDGES) {
            int s, d;
            load_edge(eiv, is32, e, s, d);
            int pos = atomicAdd(&cursor[d], 1);
            src_sorted[pos] = s;
        }
    }
}

// ---------------- per-node softmax aggregation: 2 edges/wave, 4 channels/lane ----------------

__global__ __launch_bounds__(256) void agg_kernel(
    const float* __restrict__ Q, const unsigned short* __restrict__ KV,
    const float* __restrict__ SKIP, float* __restrict__ OUT,
    const int* __restrict__ row_ptr, const int* __restrict__ src_sorted, int apply_elu)
{
    int wid  = threadIdx.x >> 6;
    int lane = threadIdx.x & 63;
    int half = lane >> 5;
    int sub  = lane & 31;
    int node = blockIdx.x * 4 + wid;
    if (node >= NNODES) return;
    size_t rb = (size_t)node * FD;

    float4 q4 = *(const float4*)(Q + rb + sub * 4);
    q4.x *= 0.125f; q4.y *= 0.125f; q4.z *= 0.125f; q4.w *= 0.125f;   // 1/sqrt(64)

    float s = 0.f;
    float4 acc = make_float4(0.f, 0.f, 0.f, 0.f);
    int e0 = row_ptr[node], e1 = row_ptr[node + 1];
    const uint4* KV4 = (const uint4*)KV;    // 8 shorts per uint4

#define PAIR_UPD(EID)                                                          \
    {                                                                          \
        int eid = (EID);                                                       \
        int valid = eid < e1;                                                  \
        int j = src_sorted[valid ? eid : e1 - 1];                              \
        uint4 wv = KV4[(size_t)j * 32 + sub];                                  \
        float kx = __uint_as_float(wv.x << 16);                                \
        float vx = __uint_as_float(wv.x & 0xffff0000u);                        \
        float ky = __uint_as_float(wv.y << 16);                                \
        float vy = __uint_as_float(wv.y & 0xffff0000u);                        \
        float kz = __uint_as_float(wv.z << 16);                                \
        float vz = __uint_as_float(wv.z & 0xffff0000u);                        \
        float kw = __uint_as_float(wv.w << 16);                                \
        float vw = __uint_as_float(wv.w & 0xffff0000u);                        \
        float p = q4.x * kx + q4.y * ky + q4.z * kz + q4.w * kw;               \
        p += __shfl_xor(p, 1, 64);                                             \
        p += __shfl_xor(p, 2, 64);                                             \
        p += __shfl_xor(p, 4, 64);                                             \
        p += __shfl_xor(p, 8, 64);         /* per-16-lane group = head sum */  \
        float w = valid ? __expf(p) : 0.f;                                     \
        s += w;                                                                \
        acc.x += w * vx; acc.y += w * vy;                                      \
        acc.z += w * vz; acc.w += w * vw;                                      \
    }

    for (int base = e0; base < e1; base += 4) {
        PAIR_UPD(base + half)
        PAIR_UPD(base + 2 + half)
    }
#undef PAIR_UPD

    // combine the two half-streams
    s += __shfl_xor(s, 32, 64);
    acc.x += __shfl_xor(acc.x, 32, 64);
    acc.y += __shfl_xor(acc.y, 32, 64);
    acc.z += __shfl_xor(acc.z, 32, 64);
    acc.w += __shfl_xor(acc.w, 32, 64);

    if (half == 0) {
        float r = 1.f / (s + 1e-16f);
        float4 sk = *(const float4*)(SKIP + rb + sub * 4);
        float ox = acc.x * r + sk.x;
        float oy = acc.y * r + sk.y;
        float oz = acc.z * r + sk.z;
        float ow = acc.w * r + sk.w;
        if (apply_elu) {
            ox = (ox > 0.f) ? ox : (__expf(ox) - 1.f);
            oy = (oy > 0.f) ? oy : (__expf(oy) - 1.f);
            oz = (oz > 0.f) ? oz : (__expf(oz) - 1.f);
            ow = (ow > 0.f) ? ow : (__expf(ow) - 1.f);
        }
        *(float4*)(OUT + rb + sub * 4) = make_float4(ox, oy, oz, ow);
    }
}

// ---------------- final classifier: out = H @ Wlin + blin  ([N,128] @ [128,40]) ----------------

__global__ void final_lin(const float* __restrict__ H, const float* __restrict__ Wl,
                          const float* __restrict__ bl, float* __restrict__ out)
{
    __shared__ float ws[FD * NCLS];    // 20 KB
    __shared__ float xs[8][FD + 1];
    int tx = threadIdx.x;              // 0..39 (col)
    int ty = threadIdx.y;              // 0..7  (row)
    int t = ty * NCLS + tx;
    for (int i = t; i < FD * NCLS; i += 320) ws[i] = Wl[i];
    int row = blockIdx.x * 8;
    for (int i = t; i < 8 * FD; i += 320) {
        int r = i >> 7, c = i & 127;
        xs[r][c] = (row + r < NNODES) ? H[(size_t)(row + r) * FD + c] : 0.f;
    }
    __syncthreads();
    float acc = bl[tx];
    #pragma unroll
    for (int k = 0; k < FD; k++) acc += xs[ty][k] * ws[k * NCLS + tx];
    if (row + ty < NNODES) out[(size_t)(row + ty) * NCLS + tx] = acc;
}

// ---------------- launch ----------------

extern "C" void kernel_launch(void* const* d_in, const int* in_sizes, int n_in,
                              void* d_out, int out_size, void* d_ws, size_t ws_size,
                              hipStream_t stream) {
    const float* x  = (const float*)d_in[0];
    const void*  ei = d_in[1];
    const float* Wq1 = (const float*)d_in[2],  *bq1 = (const float*)d_in[3];
    const float* Wk1 = (const float*)d_in[4],  *bk1 = (const float*)d_in[5];
    const float* Wv1 = (const float*)d_in[6],  *bv1 = (const float*)d_in[7];
    const float* Ws1 = (const float*)d_in[8],  *bs1 = (const float*)d_in[9];
    const float* Wq2 = (const float*)d_in[10], *bq2 = (const float*)d_in[11];
    const float* Wk2 = (const float*)d_in[12], *bk2 = (const float*)d_in[13];
    const float* Wv2 = (const float*)d_in[14], *bv2 = (const float*)d_in[15];
    const float* Ws2 = (const float*)d_in[16], *bs2 = (const float*)d_in[17];
    const float* Wlin = (const float*)d_in[18], *blin = (const float*)d_in[19];
    float* out = (float*)d_out;

    const size_t BUFE = (size_t)NNODES * FD;        // 12.8M floats
    float* Qb = (float*)d_ws;                       // Q / layer output (fp32)
    float* Cb = Qb + BUFE;                          // layer-2 Q / output (fp32)
    float* Sb = Cb + BUFE;                          // SKIP (fp32, reused per layer)
    unsigned short* KVb = (unsigned short*)(Sb + BUFE);   // N x 256 bf16 interleaved K/V
    int* row_ptr    = (int*)(KVb + (size_t)NNODES * 256); // N+1
    int* cursor     = row_ptr + (NNODES + 1);       // N
    int* src_sorted = cursor + NNODES;              // E
    int* blk_tot    = src_sorted + NEDGES;          // NB_SCAN
    int* blk_off    = blk_tot + NB_SCAN;            // NB_SCAN
    uintptr_t pal = ((uintptr_t)(blk_off + NB_SCAN) + 15) & ~(uintptr_t)15;
    short* Whi = (short*)pal;                       // 8 slots x 16384 bf16 = 256 KB
    short* Wlo = Whi + 8 * 16384;

    // ---- weight packing (one launch) + CSR histogram ----
    hipMemsetAsync(row_ptr, 0, (NNODES + 1) * sizeof(int), stream);
    pack_all<<<256, 64, 0, stream>>>(Wq1, Wk1, Wv1, Ws1, Wq2, Wk2, Wv2, Ws2, Whi, Wlo);
    hist_kernel<<<FGRID, 256, 0, stream>>>(ei, row_ptr);
    scan_blk<<<NB_SCAN, 1024, 0, stream>>>(row_ptr, cursor, blk_tot);
    scan_tops<<<1, 128, 0, stream>>>(blk_tot, blk_off);
    scan_add<<<NB_SCAN, 1024, 0, stream>>>(row_ptr, cursor, blk_off);

    // ---- layer 1 proj fused+interleaved with CSR fill ----
    proj1_fill<<<5 * PGRID, 256, 0, stream>>>(x, Whi, Wlo,
        bq1, bk1, bv1, bs1, Qb, KVb, Sb, ei, cursor, src_sorted);
    agg_kernel<<<(NNODES + 3) / 4, 256, 0, stream>>>(Qb, KVb, Sb, Qb,
        row_ptr, src_sorted, 1);

    // ---- layer 2 ----
    proj_gemm_mfma<<<PGRID, 256, 0, stream>>>(Qb, Whi + 4 * 16384, Wlo + 4 * 16384,
        bq2, bk2, bv2, bs2, Cb, KVb, Sb);
    agg_kernel<<<(NNODES + 3) / 4, 256, 0, stream>>>(Cb, KVb, Sb, Cb,
        row_ptr, src_sorted, 0);

    // ---- classifier ----
    final_lin<<<(NNODES + 7) / 8, dim3(NCLS, 8), 0, stream>>>(Cb, Wlin, blin, out);
}

// Round 16
// 803.499 us; speedup vs baseline: 1.0112x; 1.0112x over previous
//
#include <hip/hip_runtime.h>
#include <math.h>

#define NNODES 100000
#define NEDGES 1600000
#define FD 128
#define NCLS 40
#define NB_SCAN ((NNODES + 1023) / 1024)   // 98
#define PGRID ((NNODES + 63) / 64)         // 1563 proj blocks
#define FGRID ((NEDGES + 255) / 256)       // 6250 fill/hist blocks

typedef __attribute__((ext_vector_type(8))) short short8v;   // 8 x bf16 (4 VGPR)
typedef __attribute__((ext_vector_type(4))) float f32x4;

__device__ __forceinline__ unsigned short f32_to_bf16_rne(float f) {
    unsigned int u = __float_as_uint(f);
    unsigned int r = u + 0x7fff + ((u >> 16) & 1);
    return (unsigned short)(r >> 16);
}
__device__ __forceinline__ float bf16_to_f32(unsigned short h) {
    return __uint_as_float(((unsigned int)h) << 16);
}

// ---- per-block edge-dtype self-detection (int64 vs harness-narrowed int32) ----

__device__ __forceinline__ int detect_is32_block(const void* eiv, int* s_flag) {
    if (threadIdx.x < 64) {
        const long long* p = (const long long*)eiv;
        long long v = p[(size_t)threadIdx.x * (NEDGES / 64)];
        unsigned long long bad = __ballot(v < 0 || v >= (long long)NNODES);
        if (threadIdx.x == 0) *s_flag = (bad != 0ULL);
    }
    __syncthreads();
    return *s_flag;
}

__device__ __forceinline__ void load_edge(const void* eiv, int is32, int e, int& s, int& d) {
    if (is32) {
        const int* p = (const int*)eiv;
        s = p[e]; d = p[NEDGES + e];
    } else {
        const long long* p = (const long long*)eiv;
        s = (int)p[e]; d = (int)p[NEDGES + e];
    }
}

// ---------------- CSR build (dst-sorted adjacency), built once per call ----------------

__global__ __launch_bounds__(256) void hist_kernel(const void* __restrict__ eiv,
                                                   int* __restrict__ row_ptr) {
    __shared__ int sflag;
    int is32 = detect_is32_block(eiv, &sflag);
    int e = blockIdx.x * blockDim.x + threadIdx.x;
    if (e < NEDGES) {
        int s, d;
        load_edge(eiv, is32, e, s, d);
        atomicAdd(&row_ptr[d + 1], 1);
    }
}

// 98 blocks: local inclusive scan of 1024 counts
__global__ __launch_bounds__(1024) void scan_blk(int* __restrict__ row_ptr,
                                                 int* __restrict__ cursor,
                                                 int* __restrict__ blk_tot) {
    __shared__ int wtot[16];
    __shared__ int woff[16];
    int t = threadIdx.x, lane = t & 63, wid = t >> 6;
    int i = blockIdx.x * 1024 + t;
    int c = (i < NNODES) ? row_ptr[1 + i] : 0;
    int x = c;
    #pragma unroll
    for (int off = 1; off < 64; off <<= 1) {
        int y = __shfl_up(x, off, 64);
        if (lane >= off) x += y;
    }
    if (lane == 63) wtot[wid] = x;
    __syncthreads();
    if (t < 16) {
        int v = wtot[t];
        #pragma unroll
        for (int off = 1; off < 16; off <<= 1) {
            int y = __shfl_up(v, off, 64);
            if (t >= off) v += y;
        }
        woff[t] = v;
    }
    __syncthreads();
    int excl = (wid == 0) ? 0 : woff[wid - 1];
    int incl = x + excl;
    if (i < NNODES) {
        row_ptr[1 + i] = incl;
        cursor[i]      = incl - c;
    }
    if (t == 0) blk_tot[blockIdx.x] = woff[15];
}

// 1 block x 128: exclusive scan of the 98 block totals.
__global__ void scan_tops(const int* __restrict__ blk_tot, int* __restrict__ blk_off) {
    __shared__ int s[128];
    int t = threadIdx.x;
    int c0 = (t < NB_SCAN) ? blk_tot[t] : 0;
    s[t] = c0;
    __syncthreads();
    for (int d = 1; d < 128; d <<= 1) {
        int v = (t >= d) ? s[t - d] : 0;
        __syncthreads();
        s[t] += v;
        __syncthreads();
    }
    if (t < NB_SCAN) blk_off[t] = s[t] - c0;
}

// 98 blocks: add block offsets.
__global__ __launch_bounds__(1024) void scan_add(int* __restrict__ row_ptr,
                                                 int* __restrict__ cursor,
                                                 const int* __restrict__ blk_off) {
    int i = blockIdx.x * 1024 + threadIdx.x;
    if (i < NNODES) {
        int o = blk_off[blockIdx.x];
        row_ptr[1 + i] += o;
        cursor[i]      += o;
    }
}

// ---------------- W pack: all 8 slots in one launch ----------------

__global__ void pack_all(
    const float* __restrict__ W0, const float* __restrict__ W1,
    const float* __restrict__ W2, const float* __restrict__ W3,
    const float* __restrict__ W4, const float* __restrict__ W5,
    const float* __restrict__ W6, const float* __restrict__ W7,
    short* __restrict__ Whi, short* __restrict__ Wlo)
{
    int slot = blockIdx.x >> 5;        // 0..7
    int ctkk = blockIdx.x & 31;        // ct*4+kk
    const float* W = (slot == 0) ? W0 : (slot == 1) ? W1 : (slot == 2) ? W2 :
                     (slot == 3) ? W3 : (slot == 4) ? W4 : (slot == 5) ? W5 :
                     (slot == 6) ? W6 : W7;
    int lane = threadIdx.x;            // 64
    int ct = ctkk >> 2, kk = ctkk & 3;
    int col = ct * 16 + (lane & 15);
    int k0 = kk * 32 + (lane >> 4) * 8;
    short8v h, l;
    #pragma unroll
    for (int j = 0; j < 8; j++) {
        float v = W[(size_t)(k0 + j) * FD + col];
        unsigned short hh = f32_to_bf16_rne(v);
        float rem = v - bf16_to_f32(hh);
        h[j] = (short)hh;
        l[j] = (short)f32_to_bf16_rne(rem);
    }
    size_t o = ((size_t)slot * 32 + ctkk) * 512 + (size_t)lane * 8;
    *(short8v*)(Whi + o) = h;
    *(short8v*)(Wlo + o) = l;
}

// ---------------- proj body: fused 4-projection GEMM via bf16 MFMA, fp32-split 3-pass ----
// Passes: Q (fp32), merged K+V (one packed uint store per row: k | v<<16 -> no
// partial-line double-touch; values bit-identical to the old two-pass version), SKIP (fp32).

__device__ __forceinline__ void proj_body(
    int bx,
    const float* __restrict__ X,
    const short* __restrict__ Whi, const short* __restrict__ Wlo,
    const float* __restrict__ b0, const float* __restrict__ b1,
    const float* __restrict__ b2, const float* __restrict__ b3,
    float* __restrict__ Q, unsigned short* __restrict__ KV, float* __restrict__ SKIP)
{
    int wid = threadIdx.x >> 6, lane = threadIdx.x & 63;
    int rowbase = bx * 64 + wid * 16;
    int r = lane & 15, q = lane >> 4;
    int row = rowbase + r;
    unsigned int* KVu = (unsigned int*)KV;

    short8v xh[4], xl[4];
    if (row < NNODES) {
        const float* xp = X + (size_t)row * FD + q * 8;
        #pragma unroll
        for (int kk = 0; kk < 4; kk++) {
            float4 v0 = *(const float4*)(xp + kk * 32);
            float4 v1 = *(const float4*)(xp + kk * 32 + 4);
            float vv[8] = {v0.x, v0.y, v0.z, v0.w, v1.x, v1.y, v1.z, v1.w};
            #pragma unroll
            for (int j = 0; j < 8; j++) {
                unsigned short h = f32_to_bf16_rne(vv[j]);
                float rem = vv[j] - bf16_to_f32(h);
                xh[kk][j] = (short)h;
                xl[kk][j] = (short)f32_to_bf16_rne(rem);
            }
        }
    } else {
        short8v z = {0, 0, 0, 0, 0, 0, 0, 0};
        #pragma unroll
        for (int kk = 0; kk < 4; kk++) { xh[kk] = z; xl[kk] = z; }
    }

#define MFMA3(ACC, WPH, WPL)                                                      \
    _Pragma("unroll")                                                             \
    for (int kk = 0; kk < 4; kk++) {                                              \
        short8v bh = *(const short8v*)((WPH) + kk * 512);                         \
        short8v bl = *(const short8v*)((WPL) + kk * 512);                         \
        ACC = __builtin_amdgcn_mfma_f32_16x16x32_bf16(xh[kk], bh, ACC, 0, 0, 0);  \
        ACC = __builtin_amdgcn_mfma_f32_16x16x32_bf16(xl[kk], bh, ACC, 0, 0, 0);  \
        ACC = __builtin_amdgcn_mfma_f32_16x16x32_bf16(xh[kk], bl, ACC, 0, 0, 0);  \
    }

    // ---- pass Q (slot 0) ----
    #pragma unroll
    for (int ct = 0; ct < 8; ct++) {
        const short* wp = Whi + ((size_t)(0 * 8 + ct) * 4) * 512 + (size_t)lane * 8;
        const short* lp = Wlo + ((size_t)(0 * 8 + ct) * 4) * 512 + (size_t)lane * 8;
        f32x4 acc = {0.f, 0.f, 0.f, 0.f};
        MFMA3(acc, wp, lp)
        float bb = b0[ct * 16 + r];
        int e = ct * 16 + r;
        #pragma unroll
        for (int j = 0; j < 4; j++) {
            int ro = rowbase + q * 4 + j;              // D: col=lane&15, row=(lane>>4)*4+j
            if (ro < NNODES) Q[(size_t)ro * FD + e] = acc[j] + bb;
        }
    }

    // ---- pass K+V merged (slots 1,2): one packed uint store per (row, e) ----
    #pragma unroll
    for (int ct = 0; ct < 8; ct++) {
        const short* wpk = Whi + ((size_t)(1 * 8 + ct) * 4) * 512 + (size_t)lane * 8;
        const short* lpk = Wlo + ((size_t)(1 * 8 + ct) * 4) * 512 + (size_t)lane * 8;
        f32x4 acc = {0.f, 0.f, 0.f, 0.f};
        MFMA3(acc, wpk, lpk)
        float bbk = b1[ct * 16 + r];
        unsigned int k16[4];
        #pragma unroll
        for (int j = 0; j < 4; j++) k16[j] = f32_to_bf16_rne(acc[j] + bbk);

        const short* wpv = Whi + ((size_t)(2 * 8 + ct) * 4) * 512 + (size_t)lane * 8;
        const short* lpv = Wlo + ((size_t)(2 * 8 + ct) * 4) * 512 + (size_t)lane * 8;
        f32x4 accv = {0.f, 0.f, 0.f, 0.f};
        MFMA3(accv, wpv, lpv)
        float bbv = b2[ct * 16 + r];
        int e = ct * 16 + r;
        #pragma unroll
        for (int j = 0; j < 4; j++) {
            int ro = rowbase + q * 4 + j;
            if (ro < NNODES) {
                unsigned int v16 = f32_to_bf16_rne(accv[j] + bbv);
                KVu[(size_t)ro * 128 + e] = k16[j] | (v16 << 16);   // low short=k, high=v
            }
        }
    }

    // ---- pass SKIP (slot 3) ----
    #pragma unroll
    for (int ct = 0; ct < 8; ct++) {
        const short* wp = Whi + ((size_t)(3 * 8 + ct) * 4) * 512 + (size_t)lane * 8;
        const short* lp = Wlo + ((size_t)(3 * 8 + ct) * 4) * 512 + (size_t)lane * 8;
        f32x4 acc = {0.f, 0.f, 0.f, 0.f};
        MFMA3(acc, wp, lp)
        float bb = b3[ct * 16 + r];
        int e = ct * 16 + r;
        #pragma unroll
        for (int j = 0; j < 4; j++) {
            int ro = rowbase + q * 4 + j;
            if (ro < NNODES) SKIP[(size_t)ro * FD + e] = acc[j] + bb;
        }
    }
#undef MFMA3
}

// standalone proj (layer 2)
__global__ __launch_bounds__(256) void proj_gemm_mfma(
    const float* __restrict__ X,
    const short* __restrict__ Whi, const short* __restrict__ Wlo,
    const float* __restrict__ b0, const float* __restrict__ b1,
    const float* __restrict__ b2, const float* __restrict__ b3,
    float* __restrict__ Q, unsigned short* __restrict__ KV, float* __restrict__ SKIP)
{
    proj_body(blockIdx.x, X, Whi, Wlo, b0, b1, b2, b3, Q, KV, SKIP);
}

// ---- fused + INTERLEAVED: b%5==0 -> proj block b/5; else fill block (b - b/5 - 1) ----
// 1:4 stripe keeps proj and fill blocks co-resident on every CU from t=0 (R14: 268->185us).

__global__ __launch_bounds__(256) void proj1_fill(
    const float* __restrict__ X,
    const short* __restrict__ Whi, const short* __restrict__ Wlo,
    const float* __restrict__ b0, const float* __restrict__ b1,
    const float* __restrict__ b2, const float* __restrict__ b3,
    float* __restrict__ Q, unsigned short* __restrict__ KV, float* __restrict__ SKIP,
    const void* __restrict__ eiv, int* __restrict__ cursor, int* __restrict__ src_sorted)
{
    int b = blockIdx.x;
    if (b % 5 == 0) {
        proj_body(b / 5, X, Whi, Wlo, b0, b1, b2, b3, Q, KV, SKIP);
    } else {
        __shared__ int sflag;
        int is32 = detect_is32_block(eiv, &sflag);
        int fb = b - b / 5 - 1;                 // bijective onto [0, 4*PGRID)
        int e = fb * 256 + threadIdx.x;
        if (e < NEDGES) {
            int s, d;
            load_edge(eiv, is32, e, s, d);
            int pos = atomicAdd(&cursor[d], 1);
            src_sorted[pos] = s;
        }
    }
}

// ---------------- per-node softmax aggregation: 2 edges/wave, 4 channels/lane ----------------

__global__ __launch_bounds__(256) void agg_kernel(
    const float* __restrict__ Q, const unsigned short* __restrict__ KV,
    const float* __restrict__ SKIP, float* __restrict__ OUT,
    const int* __restrict__ row_ptr, const int* __restrict__ src_sorted, int apply_elu)
{
    int wid  = threadIdx.x >> 6;
    int lane = threadIdx.x & 63;
    int half = lane >> 5;
    int sub  = lane & 31;
    int node = blockIdx.x * 4 + wid;
    if (node >= NNODES) return;
    size_t rb = (size_t)node * FD;

    float4 q4 = *(const float4*)(Q + rb + sub * 4);
    q4.x *= 0.125f; q4.y *= 0.125f; q4.z *= 0.125f; q4.w *= 0.125f;   // 1/sqrt(64)

    float s = 0.f;
    float4 acc = make_float4(0.f, 0.f, 0.f, 0.f);
    int e0 = row_ptr[node], e1 = row_ptr[node + 1];
    const uint4* KV4 = (const uint4*)KV;    // 8 shorts per uint4

#define PAIR_UPD(EID)                                                          \
    {                                                                          \
        int eid = (EID);                                                       \
        int valid = eid < e1;                                                  \
        int j = src_sorted[valid ? eid : e1 - 1];                              \
        uint4 wv = KV4[(size_t)j * 32 + sub];                                  \
        float kx = __uint_as_float(wv.x << 16);                                \
        float vx = __uint_as_float(wv.x & 0xffff0000u);                        \
        float ky = __uint_as_float(wv.y << 16);                                \
        float vy = __uint_as_float(wv.y & 0xffff0000u);                        \
        float kz = __uint_as_float(wv.z << 16);                                \
        float vz = __uint_as_float(wv.z & 0xffff0000u);                        \
        float kw = __uint_as_float(wv.w << 16);                                \
        float vw = __uint_as_float(wv.w & 0xffff0000u);                        \
        float p = q4.x * kx + q4.y * ky + q4.z * kz + q4.w * kw;               \
        p += __shfl_xor(p, 1, 64);                                             \
        p += __shfl_xor(p, 2, 64);                                             \
        p += __shfl_xor(p, 4, 64);                                             \
        p += __shfl_xor(p, 8, 64);         /* per-16-lane group = head sum */  \
        float w = valid ? __expf(p) : 0.f;                                     \
        s += w;                                                                \
        acc.x += w * vx; acc.y += w * vy;                                      \
        acc.z += w * vz; acc.w += w * vw;                                      \
    }

    for (int base = e0; base < e1; base += 4) {
        PAIR_UPD(base + half)
        PAIR_UPD(base + 2 + half)
    }
#undef PAIR_UPD

    // combine the two half-streams
    s += __shfl_xor(s, 32, 64);
    acc.x += __shfl_xor(acc.x, 32, 64);
    acc.y += __shfl_xor(acc.y, 32, 64);
    acc.z += __shfl_xor(acc.z, 32, 64);
    acc.w += __shfl_xor(acc.w, 32, 64);

    if (half == 0) {
        float r = 1.f / (s + 1e-16f);
        float4 sk = *(const float4*)(SKIP + rb + sub * 4);
        float ox = acc.x * r + sk.x;
        float oy = acc.y * r + sk.y;
        float oz = acc.z * r + sk.z;
        float ow = acc.w * r + sk.w;
        if (apply_elu) {
            ox = (ox > 0.f) ? ox : (__expf(ox) - 1.f);
            oy = (oy > 0.f) ? oy : (__expf(oy) - 1.f);
            oz = (oz > 0.f) ? oz : (__expf(oz) - 1.f);
            ow = (ow > 0.f) ? ow : (__expf(ow) - 1.f);
        }
        *(float4*)(OUT + rb + sub * 4) = make_float4(ox, oy, oz, ow);
    }
}

// ---------------- final classifier: out = H @ Wlin + blin  ([N,128] @ [128,40]) ----------------

__global__ void final_lin(const float* __restrict__ H, const float* __restrict__ Wl,
                          const float* __restrict__ bl, float* __restrict__ out)
{
    __shared__ float ws[FD * NCLS];    // 20 KB
    __shared__ float xs[8][FD + 1];
    int tx = threadIdx.x;              // 0..39 (col)
    int ty = threadIdx.y;              // 0..7  (row)
    int t = ty * NCLS + tx;
    for (int i = t; i < FD * NCLS; i += 320) ws[i] = Wl[i];
    int row = blockIdx.x * 8;
    for (int i = t; i < 8 * FD; i += 320) {
        int r = i >> 7, c = i & 127;
        xs[r][c] = (row + r < NNODES) ? H[(size_t)(row + r) * FD + c] : 0.f;
    }
    __syncthreads();
    float acc = bl[tx];
    #pragma unroll
    for (int k = 0; k < FD; k++) acc += xs[ty][k] * ws[k * NCLS + tx];
    if (row + ty < NNODES) out[(size_t)(row + ty) * NCLS + tx] = acc;
}

// ---------------- launch ----------------

extern "C" void kernel_launch(void* const* d_in, const int* in_sizes, int n_in,
                              void* d_out, int out_size, void* d_ws, size_t ws_size,
                              hipStream_t stream) {
    const float* x  = (const float*)d_in[0];
    const void*  ei = d_in[1];
    const float* Wq1 = (const float*)d_in[2],  *bq1 = (const float*)d_in[3];
    const float* Wk1 = (const float*)d_in[4],  *bk1 = (const float*)d_in[5];
    const float* Wv1 = (const float*)d_in[6],  *bv1 = (const float*)d_in[7];
    const float* Ws1 = (const float*)d_in[8],  *bs1 = (const float*)d_in[9];
    const float* Wq2 = (const float*)d_in[10], *bq2 = (const float*)d_in[11];
    const float* Wk2 = (const float*)d_in[12], *bk2 = (const float*)d_in[13];
    const float* Wv2 = (const float*)d_in[14], *bv2 = (const float*)d_in[15];
    const float* Ws2 = (const float*)d_in[16], *bs2 = (const float*)d_in[17];
    const float* Wlin = (const float*)d_in[18], *blin = (const float*)d_in[19];
    float* out = (float*)d_out;

    const size_t BUFE = (size_t)NNODES * FD;        // 12.8M floats
    float* Qb = (float*)d_ws;                       // Q / layer output (fp32)
    float* Cb = Qb + BUFE;                          // layer-2 Q / output (fp32)
    float* Sb = Cb + BUFE;                          // SKIP (fp32, reused per layer)
    unsigned short* KVb = (unsigned short*)(Sb + BUFE);   // N x 256 bf16 interleaved K/V
    int* row_ptr    = (int*)(KVb + (size_t)NNODES * 256); // N+1
    int* cursor     = row_ptr + (NNODES + 1);       // N
    int* src_sorted = cursor + NNODES;              // E
    int* blk_tot    = src_sorted + NEDGES;          // NB_SCAN
    int* blk_off    = blk_tot + NB_SCAN;            // NB_SCAN
    uintptr_t pal = ((uintptr_t)(blk_off + NB_SCAN) + 15) & ~(uintptr_t)15;
    short* Whi = (short*)pal;                       // 8 slots x 16384 bf16 = 256 KB
    short* Wlo = Whi + 8 * 16384;

    // ---- weight packing (one launch) + CSR histogram ----
    hipMemsetAsync(row_ptr, 0, (NNODES + 1) * sizeof(int), stream);
    pack_all<<<256, 64, 0, stream>>>(Wq1, Wk1, Wv1, Ws1, Wq2, Wk2, Wv2, Ws2, Whi, Wlo);
    hist_kernel<<<FGRID, 256, 0, stream>>>(ei, row_ptr);
    scan_blk<<<NB_SCAN, 1024, 0, stream>>>(row_ptr, cursor, blk_tot);
    scan_tops<<<1, 128, 0, stream>>>(blk_tot, blk_off);
    scan_add<<<NB_SCAN, 1024, 0, stream>>>(row_ptr, cursor, blk_off);

    // ---- layer 1 proj fused+interleaved with CSR fill ----
    proj1_fill<<<5 * PGRID, 256, 0, stream>>>(x, Whi, Wlo,
        bq1, bk1, bv1, bs1, Qb, KVb, Sb, ei, cursor, src_sorted);
    agg_kernel<<<(NNODES + 3) / 4, 256, 0, stream>>>(Qb, KVb, Sb, Qb,
        row_ptr, src_sorted, 1);

    // ---- layer 2 ----
    proj_gemm_mfma<<<PGRID, 256, 0, stream>>>(Qb, Whi + 4 * 16384, Wlo + 4 * 16384,
        bq2, bk2, bv2, bs2, Cb, KVb, Sb);
    agg_kernel<<<(NNODES + 3) / 4, 256, 0, stream>>>(Cb, KVb, Sb, Cb,
        row_ptr, src_sorted, 0);

    // ---- classifier ----
    final_lin<<<(NNODES + 7) / 8, dim3(NCLS, 8), 0, stream>>>(Cb, Wlin, blin, out);
}